// Round 9
// baseline (179.042 us; speedup 1.0000x reference)
//
#include <hip/hip_runtime.h>

#define NB 4
#define NS 2048
#define ND 768
#define NH 12
#define NDH 64
#define NT (NS / 128)
#define SSCALE 0.18033688011112043f   // (1/sqrt(64)) * log2(e)

typedef __bf16 bf16x8 __attribute__((ext_vector_type(8)));
typedef float  f32x4  __attribute__((ext_vector_type(4)));
typedef unsigned int u32;

#define MFMA16(a, b, c) __builtin_amdgcn_mfma_f32_16x16x32_bf16(a, b, c, 0, 0, 0)

__device__ __forceinline__ u32 packbf(float a, float b) {
    u32 ua = __builtin_bit_cast(u32, a) + 0x8000u;
    u32 ub = __builtin_bit_cast(u32, b) + 0x8000u;
    return __builtin_amdgcn_perm(ub, ua, 0x07060302u);
}

__device__ __forceinline__ bf16x8 cvt8(float4 a, float4 b) {
    union { u32 u[4]; bf16x8 v; } r;
    r.u[0] = packbf(a.x, a.y); r.u[1] = packbf(a.z, a.w);
    r.u[2] = packbf(b.x, b.y); r.u[3] = packbf(b.z, b.w);
    return r.v;
}

__device__ __forceinline__ __bf16 f2bf(float f) {
    u32 u = __builtin_bit_cast(u32, f) + 0x8000u;
    unsigned short s = (unsigned short)(u >> 16);
    return __builtin_bit_cast(__bf16, s);
}

// ---------------------------------------------------------------------------
// Kernel 0: weight pre-conversion fp32 -> bf16, row-major [h][e][d] kept.
// 3*49152 elems. Makes proj's A-fragments direct b128 loads (no per-block cvt).
// ---------------------------------------------------------------------------
__global__ __launch_bounds__(256) void wprep_kernel(
    const float* __restrict__ wq, const float* __restrict__ wk,
    const float* __restrict__ wv,
    __bf16* __restrict__ wqb, __bf16* __restrict__ wkb, __bf16* __restrict__ wvb)
{
    const int i = (blockIdx.x * 256 + threadIdx.x) * 4;   // 48 blocks: 49152 elems
    float4 a;
    uint2 p;
    a = *(const float4*)(wq + i); p.x = packbf(a.x, a.y); p.y = packbf(a.z, a.w);
    *(uint2*)(wqb + i) = p;
    a = *(const float4*)(wk + i); p.x = packbf(a.x, a.y); p.y = packbf(a.z, a.w);
    *(uint2*)(wkb + i) = p;
    a = *(const float4*)(wv + i); p.x = packbf(a.x, a.y); p.y = packbf(a.z, a.w);
    *(uint2*)(wvb + i) = p;
}

// ---------------------------------------------------------------------------
// Kernel 1: QKV projections — X READ ONCE. Block = (32 s-rows, head-group of
// 6, b); grid (64,2,4)=512. X tile (32 x 384) staged once (fp32->bf16, pitch
// 392 = 2-way-free banks); all 6 heads computed from it. Wave w owns e-slice
// [w*16,w*16+16) for every head. Weights read as frag-ready bf16 (wprep).
// Q/K: direct C-layout uint2 stores (L2 merges the 32-B row segments).
// V: wave-private 16x36 mini-slab transpose (in-order DS, barrier-free),
// then 16B/lane coalesced global stores. One barrier per block total.
//   qws,kws: [b*H+h][s][64] bf16 (Q pre-scaled by SSCALE)
//   vtws:    [b*H+h][e][S]  bf16 with within-32 column perm
//            pos(k32) = (col>>2)*8 + nt*4 + (col&3),  k32 = nt*16+col
// ---------------------------------------------------------------------------
__global__ __launch_bounds__(256, 4) void proj_kernel(
    const float* __restrict__ x,
    const __bf16* __restrict__ wqb, const float* __restrict__ bq,
    const __bf16* __restrict__ wkb, const float* __restrict__ bk,
    const __bf16* __restrict__ wvb, const float* __restrict__ bv,
    __bf16* __restrict__ qws, __bf16* __restrict__ kws, __bf16* __restrict__ vtws)
{
    const int st = blockIdx.x, hg = blockIdx.y, b = blockIdx.z;
    const int s0 = st * 32;
    const int tid = threadIdx.x;

    __shared__ __align__(16) __bf16 Xs[32 * 392];
    __shared__ __align__(16) __bf16 Vslab[4][16 * 36];

    const int lane = tid & 63, w = tid >> 6, col = lane & 15, quad = lane >> 4;

    {   // stage X: 32 rows x 384 cols (this head-group's d-slice), once
        const int row = tid >> 3, seg = tid & 7;
        const float* xr = x + (size_t)(b * NS + s0 + row) * ND + hg * 384 + seg * 48;
#pragma unroll
        for (int j = 0; j < 6; ++j) {
            const float4 f0 = *(const float4*)(xr + j * 8);
            const float4 f1 = *(const float4*)(xr + j * 8 + 4);
            *(bf16x8*)&Xs[row * 392 + seg * 48 + j * 8] = cvt8(f0, f1);
        }
    }
    __syncthreads();

    for (int hl = 0; hl < 6; ++hl) {
        const int h = hg * 6 + hl;
        const size_t bh = (size_t)(b * NH + h);

        // A-fragments: frag-ready bf16 weights, rows e = h*64 + w*16 + col
        const size_t wr = ((size_t)(h * NDH + w * 16 + col)) * NDH + quad * 8;
        const bf16x8 aq0 = *(const bf16x8*)(wqb + wr);
        const bf16x8 aq1 = *(const bf16x8*)(wqb + wr + 32);
        const bf16x8 ak0 = *(const bf16x8*)(wkb + wr);
        const bf16x8 ak1 = *(const bf16x8*)(wkb + wr + 32);
        const bf16x8 av0 = *(const bf16x8*)(wvb + wr);
        const bf16x8 av1 = *(const bf16x8*)(wvb + wr + 32);

        // biases for rows e = w*16 + quad*4 + (0..3)
        const float4 bqv = *(const float4*)(bq + h * NDH + w * 16 + quad * 4);
        const float4 bkv = *(const float4*)(bk + h * NDH + w * 16 + quad * 4);
        const float4 bvv = *(const float4*)(bv + h * NDH + w * 16 + quad * 4);
        const float bqs[4] = {bqv.x * SSCALE, bqv.y * SSCALE, bqv.z * SSCALE, bqv.w * SSCALE};
        const float bks[4] = {bkv.x, bkv.y, bkv.z, bkv.w};
        const float bvs[4] = {bvv.x, bvv.y, bvv.z, bvv.w};

#pragma unroll
        for (int nt = 0; nt < 2; ++nt) {
            const bf16x8 xb0 = *(const bf16x8*)&Xs[(nt * 16 + col) * 392 + hl * 64 + quad * 8];
            const bf16x8 xb1 = *(const bf16x8*)&Xs[(nt * 16 + col) * 392 + hl * 64 + 32 + quad * 8];
            f32x4 cq = {0.f, 0.f, 0.f, 0.f};
            f32x4 ck = {0.f, 0.f, 0.f, 0.f};
            f32x4 cv = {0.f, 0.f, 0.f, 0.f};
            cq = MFMA16(aq0, xb0, cq); cq = MFMA16(aq1, xb1, cq);
            ck = MFMA16(ak0, xb0, ck); ck = MFMA16(ak1, xb1, ck);
            cv = MFMA16(av0, xb0, cv); cv = MFMA16(av1, xb1, cv);

            // Q (scaled), K: direct uint2 stores (4 e-contiguous bf16)
            union { u32 u[2]; uint2 v; } pq, pk;
            pq.u[0] = packbf(fmaf(cq[0], SSCALE, bqs[0]), fmaf(cq[1], SSCALE, bqs[1]));
            pq.u[1] = packbf(fmaf(cq[2], SSCALE, bqs[2]), fmaf(cq[3], SSCALE, bqs[3]));
            pk.u[0] = packbf(ck[0] + bks[0], ck[1] + bks[1]);
            pk.u[1] = packbf(ck[2] + bks[2], ck[3] + bks[3]);
            const size_t goff = (bh * NS + s0 + nt * 16 + col) * NDH + w * 16 + quad * 4;
            *(uint2*)(qws + goff) = pq.v;
            *(uint2*)(kws + goff) = pk.v;

            // V into wave-private mini-slab [e_local][pos], permuted columns
            const int pos = (col >> 2) * 8 + nt * 4 + (col & 3);
#pragma unroll
            for (int rr = 0; rr < 4; ++rr)
                Vslab[w][(quad * 4 + rr) * 36 + pos] = f2bf(cv[rr] + bvs[rr]);
        }

        // V readback + coalesced global store (in-order DS: no barrier needed)
        {
            const int row = lane >> 2, scol = (lane & 3) * 8;
            const uint4 vv = *(const uint4*)&Vslab[w][row * 36 + scol];
            *(uint4*)(vtws + (bh * NDH + w * 16 + row) * NS + s0 + scol) = vv;
        }
    }
}

// ---------------------------------------------------------------------------
// Kernel 2: flash attention (R8 body — no-max exp2, S^T split-K, barrier-free
// register staging) + XCD-COLOCATED 1-D grid: bh = (bid&7) + 8*(bid>>8),
// qt = (bid>>3)&31. Under round-robin dispatch->XCD, all 32 q-blocks of one
// (b,h) land on one XCD; 6 bh x 512 KB K/V = 3 MB fits the 4 MB per-XCD L2,
// so the 16x K/V re-read is served from L2 instead of L3.
// ---------------------------------------------------------------------------
__global__ __launch_bounds__(256, 3) void attn_kernel(
    const __bf16* __restrict__ qws, const __bf16* __restrict__ kws,
    const __bf16* __restrict__ vtws, float* __restrict__ out)
{
    const int bid = blockIdx.x;
    const int bh_i = (bid & 7) + 8 * (bid >> 8);
    const int qt = (bid >> 3) & 31;
    const int b = bh_i / NH, h = bh_i - b * NH;
    const int q0 = qt * 64;
    const int tid = threadIdx.x;

    __shared__ __align__(16) unsigned char smem[36864];
    __bf16* lds = (__bf16*)smem;
    float* slabA = (float*)smem;                 // 64 x 68 f32
    float* slabB = (float*)(smem + 17408);       // 64 x 68 f32
    float* lbuf  = (float*)(smem + 34816);       // 256 f32

    const size_t bh = (size_t)bh_i;
    const int lane = tid & 63, w = tid >> 6, col = lane & 15, quad = lane >> 4;
    const int L = lane;

    // Q B-fragments in registers (rows q = q0+nt*16+col)
    bf16x8 qb0[4], qb1[4];
#pragma unroll
    for (int nt = 0; nt < 4; ++nt) {
        const __bf16* qp = qws + (bh * NS + q0 + nt * 16 + col) * NDH + quad * 8;
        qb0[nt] = *(const bf16x8*)(qp);
        qb1[nt] = *(const bf16x8*)(qp + 32);
    }

    // staging sources (XOR swizzle baked into SOURCE address; R5-R8 proven)
    const __bf16* ksrc = kws + bh * (size_t)(NS * NDH)
                       + (size_t)(w * 32 + (L >> 3)) * NDH + ((L & 7) ^ (L >> 3)) * 8;
    const __bf16* vsrc = vtws + bh * (size_t)(NDH * NS)
                       + (size_t)(L >> 2) * NS + w * 32 + ((L & 3) ^ ((L >> 3) & 3)) * 8;
    const int kb_lds = w * 2048 + L * 8;           // elems
    const int vb_lds = 8192 + w * 2048 + L * 8;    // elems

    // swizzled LDS read offsets (elems)
    const int cx7 = col & 7;
    int ka_off[2][2], va_off[4];
#pragma unroll
    for (int mt = 0; mt < 2; ++mt) {
        const int base = w * 2048 + (mt * 16 + col) * 64;
        ka_off[mt][0] = base + ((quad)     ^ cx7) * 8;
        ka_off[mt][1] = base + ((quad + 4) ^ cx7) * 8;
    }
#pragma unroll
    for (int dt = 0; dt < 4; ++dt)
        va_off[dt] = 8192 + w * 2048 + (dt * 16 + col) * 32 + (quad ^ ((col >> 1) & 3)) * 8;

    float l[4] = {0.f, 0.f, 0.f, 0.f};
    f32x4 o[4][4];
#pragma unroll
    for (int dt = 0; dt < 4; ++dt)
#pragma unroll
        for (int nt = 0; nt < 4; ++nt) o[dt][nt] = (f32x4){0.f, 0.f, 0.f, 0.f};

    // prologue: stage tile 0 (global->reg->LDS), wave-private, no barrier
    uint4 kstg[4], vstg[4];
#pragma unroll
    for (int i = 0; i < 4; ++i) kstg[i] = *(const uint4*)(ksrc + i * 512);
#pragma unroll
    for (int i = 0; i < 4; ++i) vstg[i] = *(const uint4*)(vsrc + (size_t)i * 16 * NS);
#pragma unroll
    for (int i = 0; i < 4; ++i) *(uint4*)&lds[kb_lds + i * 512] = kstg[i];
#pragma unroll
    for (int i = 0; i < 4; ++i) *(uint4*)&lds[vb_lds + i * 512] = vstg[i];

    for (int kt = 0; kt < NT; ++kt) {
        if (kt + 1 < NT) {   // next tile's global loads first: full-iter slack
            const __bf16* ks = ksrc + (size_t)(kt + 1) * 8192;
            const __bf16* vs = vsrc + (kt + 1) * 128;
#pragma unroll
            for (int i = 0; i < 4; ++i) kstg[i] = *(const uint4*)(ks + i * 512);
#pragma unroll
            for (int i = 0; i < 4; ++i) vstg[i] = *(const uint4*)(vs + (size_t)i * 16 * NS);
        }

        bf16x8 ka[2][2], va[4];
#pragma unroll
        for (int mt = 0; mt < 2; ++mt) {
            ka[mt][0] = *(const bf16x8*)&lds[ka_off[mt][0]];
            ka[mt][1] = *(const bf16x8*)&lds[ka_off[mt][1]];
        }
#pragma unroll
        for (int dt = 0; dt < 4; ++dt) va[dt] = *(const bf16x8*)&lds[va_off[dt]];

#pragma unroll
        for (int nt = 0; nt < 4; ++nt) {
            f32x4 sA = {0.f, 0.f, 0.f, 0.f};
            f32x4 sB = {0.f, 0.f, 0.f, 0.f};
            sA = MFMA16(ka[0][0], qb0[nt], sA); sA = MFMA16(ka[0][1], qb1[nt], sA);
            sB = MFMA16(ka[1][0], qb0[nt], sB); sB = MFMA16(ka[1][1], qb1[nt], sB);

            const float p0 = __builtin_amdgcn_exp2f(sA[0]);
            const float p1 = __builtin_amdgcn_exp2f(sA[1]);
            const float p2 = __builtin_amdgcn_exp2f(sA[2]);
            const float p3 = __builtin_amdgcn_exp2f(sA[3]);
            const float p4 = __builtin_amdgcn_exp2f(sB[0]);
            const float p5 = __builtin_amdgcn_exp2f(sB[1]);
            const float p6 = __builtin_amdgcn_exp2f(sB[2]);
            const float p7 = __builtin_amdgcn_exp2f(sB[3]);
            l[nt] += ((p0 + p1) + (p2 + p3)) + ((p4 + p5) + (p6 + p7));

            union { u32 u[4]; bf16x8 v; } pb;   // B-frag: k_mfma = quad*8+mt*4+r
            pb.u[0] = packbf(p0, p1);
            pb.u[1] = packbf(p2, p3);
            pb.u[2] = packbf(p4, p5);
            pb.u[3] = packbf(p6, p7);

#pragma unroll
            for (int dt = 0; dt < 4; ++dt)
                o[dt][nt] = MFMA16(va[dt], pb.v, o[dt][nt]);
        }

        if (kt + 1 < NT) {   // stage next tile (in-order DS pipe: safe)
#pragma unroll
            for (int i = 0; i < 4; ++i) *(uint4*)&lds[kb_lds + i * 512] = kstg[i];
#pragma unroll
            for (int i = 0; i < 4; ++i) *(uint4*)&lds[vb_lds + i * 512] = vstg[i];
        }
    }

    // cross-quad l reduction (deferred from loop)
#pragma unroll
    for (int nt = 0; nt < 4; ++nt) {
        l[nt] += __shfl_xor(l[nt], 16, 64);
        l[nt] += __shfl_xor(l[nt], 32, 64);
    }

    // split-K combine across the 4 waves (l only — no m state)
    __syncthreads();
    if (quad == 0) {
#pragma unroll
        for (int nt = 0; nt < 4; ++nt)
            lbuf[w * 64 + nt * 16 + col] = l[nt];
    }
    __syncthreads();

    float scale[4];
#pragma unroll
    for (int nt = 0; nt < 4; ++nt) {
        const int qi = nt * 16 + col;
        const float Lt = (lbuf[qi] + lbuf[64 + qi]) + (lbuf[128 + qi] + lbuf[192 + qi]);
        scale[nt] = 1.0f / Lt;
    }
    __syncthreads();
#pragma unroll
    for (int dt = 0; dt < 4; ++dt)
#pragma unroll
        for (int nt = 0; nt < 4; ++nt) o[dt][nt] *= scale[nt];

    if (w == 0 || w == 2) {
        float* s = (w == 0) ? slabA : slabB;
#pragma unroll
        for (int dt = 0; dt < 4; ++dt)
#pragma unroll
            for (int nt = 0; nt < 4; ++nt)
                *(f32x4*)&s[(nt * 16 + col) * 68 + dt * 16 + quad * 4] = o[dt][nt];
    }
    __syncthreads();
    if (w == 1 || w == 3) {
        float* s = (w == 1) ? slabA : slabB;
#pragma unroll
        for (int dt = 0; dt < 4; ++dt)
#pragma unroll
            for (int nt = 0; nt < 4; ++nt) {
                f32x4* p = (f32x4*)&s[(nt * 16 + col) * 68 + dt * 16 + quad * 4];
                *p = *p + o[dt][nt];
            }
    }
    __syncthreads();

    const int qr = tid >> 2, fq = tid & 3;
#pragma unroll
    for (int j = 0; j < 4; ++j) {
        const f32x4 a = *(const f32x4*)&slabA[qr * 68 + fq * 16 + j * 4];
        const f32x4 c = *(const f32x4*)&slabB[qr * 68 + fq * 16 + j * 4];
        *(f32x4*)&out[(size_t)(b * NS + q0 + qr) * ND + h * NDH + fq * 16 + j * 4] = a + c;
    }
}

extern "C" void kernel_launch(void* const* d_in, const int* in_sizes, int n_in,
                              void* d_out, int out_size, void* d_ws, size_t ws_size,
                              hipStream_t stream) {
    (void)in_sizes; (void)n_in; (void)out_size; (void)ws_size;
    const float* x  = (const float*)d_in[0];
    const float* wq = (const float*)d_in[1];
    const float* bq = (const float*)d_in[2];
    const float* wk = (const float*)d_in[3];
    const float* bk = (const float*)d_in[4];
    const float* wv = (const float*)d_in[5];
    const float* bv = (const float*)d_in[6];
    float* out = (float*)d_out;

    const size_t TEN = (size_t)NB * NH * NS * NDH;   // 6291456 elems
    __bf16* qws  = (__bf16*)d_ws;
    __bf16* kws  = qws + TEN;
    __bf16* vtws = kws + TEN;
    __bf16* wqb  = vtws + TEN;
    __bf16* wkb  = wqb + (size_t)NH * NDH * NDH;
    __bf16* wvb  = wkb + (size_t)NH * NDH * NDH;

    wprep_kernel<<<48, 256, 0, stream>>>(wq, wk, wv, wqb, wkb, wvb);
    dim3 pgrid(NS / 32, 2, NB);
    proj_kernel<<<pgrid, 256, 0, stream>>>(x, wqb, bq, wkb, bk, wvb, bv, qws, kws, vtws);
    attn_kernel<<<NB * NH * (NS / 64), 256, 0, stream>>>(qws, kws, vtws, out);
}